// Round 2
// baseline (498.396 us; speedup 1.0000x reference)
//
#include <hip/hip_runtime.h>
#include <hip/hip_bf16.h>
#include <cstdint>
#include <cstddef>

#define Bn 64
#define Mn 512
#define Dn 2048
#define Kn 32
#define EPSF 1e-12f

typedef __attribute__((ext_vector_type(8))) __bf16 bf16x8;
typedef __attribute__((ext_vector_type(4))) float f32x4;

// ---------------- K0: W -> bf16; zero colsum & ssq accumulators ---------------
__global__ __launch_bounds__(256) void k0_prep(const float* __restrict__ W,
                                               __bf16* __restrict__ Wb,
                                               float* __restrict__ colsum,
                                               float* __restrict__ ssq) {
  int idx = blockIdx.x * 256 + threadIdx.x;
  if (idx < Kn * Dn) Wb[idx] = (__bf16)W[idx];
  if (idx < Bn * Kn) { colsum[idx] = 0.f; ssq[idx] = 0.f; }
}

// ---------------- K1: logits (bf16 MFMA) + fused softmax -> sa' bf16 + colsum --
// One wave per 16 rows. All K=32 logits of a row live in this wave's acc0/acc1
// (col=lane&15 -> cluster, row=q*4+r), so softmax is pure cross-lane shuffles.
// Writes sa'[m][k] = sa*invnorm as bf16 row-major; colsum via 32 atomics/wave.
__global__ __launch_bounds__(256) void k1_logits_softmax(const float* __restrict__ x,
                                                         const __bf16* __restrict__ Wb,
                                                         __bf16* __restrict__ saP,
                                                         float* __restrict__ colsum) {
  int wv = threadIdx.x >> 6, lane = threadIdx.x & 63;
  int mr = lane & 15, q = lane >> 4;
  int row0 = (blockIdx.x * 4 + wv) * 16;
  int b = row0 >> 9;                       // 512 rows per b; block spans 64 rows
  const float* xp = x + (size_t)(row0 + mr) * Dn + q * 8;
  const __bf16* wp = Wb + (size_t)mr * Dn + q * 8;
  f32x4 acc0 = {0.f, 0.f, 0.f, 0.f};
  f32x4 acc1 = {0.f, 0.f, 0.f, 0.f};
  float ssq = 0.f;
#pragma unroll 2
  for (int s = 0; s < 64; ++s) {
    f32x4 xa = *(const f32x4*)(xp + s * 32);
    f32x4 xb = *(const f32x4*)(xp + s * 32 + 4);
    bf16x8 af;
    af[0] = (__bf16)xa[0]; af[1] = (__bf16)xa[1];
    af[2] = (__bf16)xa[2]; af[3] = (__bf16)xa[3];
    af[4] = (__bf16)xb[0]; af[5] = (__bf16)xb[1];
    af[6] = (__bf16)xb[2]; af[7] = (__bf16)xb[3];
    ssq = fmaf(xa[0], xa[0], ssq); ssq = fmaf(xa[1], xa[1], ssq);
    ssq = fmaf(xa[2], xa[2], ssq); ssq = fmaf(xa[3], xa[3], ssq);
    ssq = fmaf(xb[0], xb[0], ssq); ssq = fmaf(xb[1], xb[1], ssq);
    ssq = fmaf(xb[2], xb[2], ssq); ssq = fmaf(xb[3], xb[3], ssq);
    bf16x8 b0 = *(const bf16x8*)(wp + s * 32);
    bf16x8 b1 = *(const bf16x8*)(wp + (size_t)16 * Dn + s * 32);
    acc0 = __builtin_amdgcn_mfma_f32_16x16x32_bf16(af, b0, acc0, 0, 0, 0);
    acc1 = __builtin_amdgcn_mfma_f32_16x16x32_bf16(af, b1, acc1, 0, 0, 0);
  }
  // full row-sumsq: lane (mr,q) holds partial of row mr over its d-subset
  ssq += __shfl_xor(ssq, 16);
  ssq += __shfl_xor(ssq, 32);
  float invb = 1.f / fmaxf(sqrtf(ssq), EPSF);   // invnorm of row row0+mr
  float cs0 = 0.f, cs1 = 0.f;
#pragma unroll
  for (int r = 0; r < 4; ++r) {
    float inv = __shfl(invb, q * 4 + r);        // invnorm of row row0+q*4+r
    float v0 = acc0[r] * inv, v1 = acc1[r] * inv;
    float mx = fmaxf(v0, v1);                   // max over k: across 16 mr-lanes
    mx = fmaxf(mx, __shfl_xor(mx, 1));
    mx = fmaxf(mx, __shfl_xor(mx, 2));
    mx = fmaxf(mx, __shfl_xor(mx, 4));
    mx = fmaxf(mx, __shfl_xor(mx, 8));
    float e0 = __expf(v0 - mx), e1 = __expf(v1 - mx);
    float sm = e0 + e1;
    sm += __shfl_xor(sm, 1); sm += __shfl_xor(sm, 2);
    sm += __shfl_xor(sm, 4); sm += __shfl_xor(sm, 8);
    float rs = 1.f / sm;
    float sa0 = e0 * rs, sa1 = e1 * rs;
    size_t ro = (size_t)(row0 + q * 4 + r) * Kn;
    saP[ro + mr]      = (__bf16)(sa0 * inv);    // sa' = sa * invnorm
    saP[ro + mr + 16] = (__bf16)(sa1 * inv);
    cs0 += sa0; cs1 += sa1;
  }
  cs0 += __shfl_xor(cs0, 16); cs0 += __shfl_xor(cs0, 32);
  cs1 += __shfl_xor(cs1, 16); cs1 += __shfl_xor(cs1, 32);
  if (lane < 16) {
    atomicAdd(&colsum[b * Kn + mr], cs0);
    atomicAdd(&colsum[b * Kn + mr + 16], cs1);
  }
}

// ---------------- K3: agg via VALU FMA (no transpose, no MFMA) -----------------
// Thread owns one d-column; 32 fp32 accumulators over k. x read ONCE, fp32,
// coalesced (wave = 256 B contiguous per m). sa' rows broadcast from LDS
// (same-address b128 reads = free broadcast). vlad = agg - colsum*cent (fp32).
#define MT 128
__global__ __launch_bounds__(256) void k3_agg(const float* __restrict__ x,
                                              const __bf16* __restrict__ saP,
                                              const float* __restrict__ colsum,
                                              const float* __restrict__ cent,
                                              float* __restrict__ vlad,
                                              float* __restrict__ ssq) {
  __shared__ float sa_t[MT * Kn];   // 16 KB, tile of sa' converted to f32
  __shared__ float csl[Kn];
  int b = blockIdx.x >> 3;
  int d = (blockIdx.x & 7) * 256 + threadIdx.x;
  int t = threadIdx.x;
  if (t < Kn) csl[t] = colsum[b * Kn + t];
  float acc[Kn];
#pragma unroll
  for (int k = 0; k < Kn; ++k) acc[k] = 0.f;
  const float* xb = x + (size_t)b * Mn * Dn + d;
  const __bf16* sb = saP + (size_t)b * Mn * Kn;
  for (int mt = 0; mt < Mn; mt += MT) {
    __syncthreads();
    // stage MT x 32 sa' bf16 -> f32 LDS (coalesced bf16x8 global reads;
    // scalar LDS writes are amortized over 128 inner iterations)
#pragma unroll
    for (int i = 0; i < 2; ++i) {
      int u = t + 256 * i;                       // unit of 8 bf16
      bf16x8 v8 = *(const bf16x8*)(sb + (size_t)(mt)*Kn + (size_t)u * 8);
#pragma unroll
      for (int j = 0; j < 8; ++j) sa_t[u * 8 + j] = (float)v8[j];
    }
    __syncthreads();
    const float* xp = xb + (size_t)mt * Dn;
#pragma unroll 2
    for (int mm = 0; mm < MT; mm += 4) {
      float xv0 = xp[0];
      float xv1 = xp[Dn];
      float xv2 = xp[2 * Dn];
      float xv3 = xp[3 * Dn];
      xp += 4 * Dn;
      const f32x4* sr0 = (const f32x4*)&sa_t[(mm + 0) * Kn];
      const f32x4* sr1 = (const f32x4*)&sa_t[(mm + 1) * Kn];
      const f32x4* sr2 = (const f32x4*)&sa_t[(mm + 2) * Kn];
      const f32x4* sr3 = (const f32x4*)&sa_t[(mm + 3) * Kn];
#pragma unroll
      for (int g = 0; g < 8; ++g) {
        f32x4 s0 = sr0[g], s1 = sr1[g], s2 = sr2[g], s3 = sr3[g];
#pragma unroll
        for (int c = 0; c < 4; ++c) {
          int k = g * 4 + c;
          acc[k] = fmaf(s0[c], xv0, acc[k]);
          acc[k] = fmaf(s1[c], xv1, acc[k]);
          acc[k] = fmaf(s2[c], xv2, acc[k]);
          acc[k] = fmaf(s3[c], xv3, acc[k]);
        }
      }
    }
  }
  int lane = t & 63;
#pragma unroll
  for (int k = 0; k < Kn; ++k) {
    float vv = acc[k] - csl[k] * cent[(size_t)k * Dn + d];
    vlad[((size_t)(b * Kn + k)) * Dn + d] = vv;
    float sq = vv * vv;
    sq += __shfl_xor(sq, 1);  sq += __shfl_xor(sq, 2);
    sq += __shfl_xor(sq, 4);  sq += __shfl_xor(sq, 8);
    sq += __shfl_xor(sq, 16); sq += __shfl_xor(sq, 32);
    if (lane == 0) atomicAdd(&ssq[b * Kn + k], sq);
  }
}

// ---------------- K4: intra-normalize per (b,k) + global L2 normalize, in place
__global__ __launch_bounds__(256) void k4_norm(float* __restrict__ out,
                                               const float* __restrict__ ssq) {
  __shared__ float rk[Kn];
  __shared__ float us[Kn];
  int b = blockIdx.x >> 4;
  int t = threadIdx.x;
  if (t < Kn) {
    float ss = ssq[b * Kn + t];
    float r = 1.f / fmaxf(sqrtf(ss), EPSF);
    rk[t] = r;
    us[t] = ss * r * r;   // = ||u_k||^2 after intra-norm
  }
  __syncthreads();
  float S = 0.f;
#pragma unroll
  for (int k = 0; k < Kn; ++k) S += us[k];
  float s = 1.f / fmaxf(sqrtf(S), EPSF);
  int chunk = blockIdx.x & 15;
  size_t base = (size_t)b * (Kn * Dn) + (size_t)chunk * 4096;
  f32x4* p = (f32x4*)(out + base);
#pragma unroll
  for (int i = 0; i < 4; ++i) {
    int idx = t + 256 * i;                        // float4 index, 0..1023
    int k = (chunk * 4096 + idx * 4) >> 11;       // 2048 floats per k
    f32x4 v = p[idx];
    float sc = rk[k] * s;
    v[0] *= sc; v[1] *= sc; v[2] *= sc; v[3] *= sc;
    p[idx] = v;
  }
}

extern "C" void kernel_launch(void* const* d_in, const int* in_sizes, int n_in,
                              void* d_out, int out_size, void* d_ws, size_t ws_size,
                              hipStream_t stream) {
  const float* x = (const float*)d_in[0];
  const float* W = (const float*)d_in[1];
  const float* cent = (const float*)d_in[2];
  float* out = (float*)d_out;
  char* ws = (char*)d_ws;
  // ws layout: Wb (128K) | colsum (8K) | ssq (8K) | saP (8M bf16)
  __bf16* Wb = (__bf16*)ws;
  float* colsum = (float*)(ws + 131072);
  float* ssqb = (float*)(ws + 131072 + 8192);
  __bf16* saP = (__bf16*)(ws + 131072 + 16384);
  hipLaunchKernelGGL(k0_prep, dim3(256), dim3(256), 0, stream, W, Wb, colsum, ssqb);
  hipLaunchKernelGGL(k1_logits_softmax, dim3(512), dim3(256), 0, stream, x, Wb, saP, colsum);
  hipLaunchKernelGGL(k3_agg, dim3(512), dim3(256), 0, stream, x, saP, colsum, cent, out, ssqb);
  hipLaunchKernelGGL(k4_norm, dim3(1024), dim3(256), 0, stream, out, ssqb);
}

// Round 3
// 447.793 us; speedup vs baseline: 1.1130x; 1.1130x over previous
//
#include <hip/hip_runtime.h>
#include <hip/hip_bf16.h>
#include <cstdint>
#include <cstddef>

#define Bn 64
#define Mn 512
#define Dn 2048
#define Kn 32
#define EPSF 1e-12f

typedef __attribute__((ext_vector_type(8))) __bf16 bf16x8;
typedef __attribute__((ext_vector_type(4))) __bf16 bf16x4;
typedef __attribute__((ext_vector_type(4))) float f32x4;

// ---------------- K0: W -> bf16; zero colsum & ssq accumulators ---------------
__global__ __launch_bounds__(256) void k0_prep(const float* __restrict__ W,
                                               __bf16* __restrict__ Wb,
                                               float* __restrict__ colsum,
                                               float* __restrict__ ssq) {
  int idx = blockIdx.x * 256 + threadIdx.x;
  if (idx < Kn * Dn) Wb[idx] = (__bf16)W[idx];
  if (idx < Bn * Kn) { colsum[idx] = 0.f; ssq[idx] = 0.f; }
}

// ---------------- K1: logits (bf16 MFMA) + fused softmax -> saT bf16 + colsum --
// One wave per 16 rows. C/D layout: lane&15 = k-cluster, (lane>>4)*4+r = m-row.
// Lane (k=mr, q) thus holds sa for 4 CONSECUTIVE m (r=0..3) of one k: writing
// k-major saT[b][k][m] is a free transpose (bf16x4 = 8 B stores).
__global__ __launch_bounds__(256) void k1_logits_softmax(const float* __restrict__ x,
                                                         const __bf16* __restrict__ Wb,
                                                         __bf16* __restrict__ saT,
                                                         float* __restrict__ colsum) {
  int wv = threadIdx.x >> 6, lane = threadIdx.x & 63;
  int mr = lane & 15, q = lane >> 4;
  int row0 = (blockIdx.x * 4 + wv) * 16;
  int b = row0 >> 9;                       // 512 rows per b
  const float* xp = x + (size_t)(row0 + mr) * Dn + q * 8;
  const __bf16* wp = Wb + (size_t)mr * Dn + q * 8;
  f32x4 acc0 = {0.f, 0.f, 0.f, 0.f};
  f32x4 acc1 = {0.f, 0.f, 0.f, 0.f};
  float ssq = 0.f;
#pragma unroll 2
  for (int s = 0; s < 64; ++s) {
    f32x4 xa = *(const f32x4*)(xp + s * 32);
    f32x4 xb = *(const f32x4*)(xp + s * 32 + 4);
    bf16x8 af;
    af[0] = (__bf16)xa[0]; af[1] = (__bf16)xa[1];
    af[2] = (__bf16)xa[2]; af[3] = (__bf16)xa[3];
    af[4] = (__bf16)xb[0]; af[5] = (__bf16)xb[1];
    af[6] = (__bf16)xb[2]; af[7] = (__bf16)xb[3];
    ssq = fmaf(xa[0], xa[0], ssq); ssq = fmaf(xa[1], xa[1], ssq);
    ssq = fmaf(xa[2], xa[2], ssq); ssq = fmaf(xa[3], xa[3], ssq);
    ssq = fmaf(xb[0], xb[0], ssq); ssq = fmaf(xb[1], xb[1], ssq);
    ssq = fmaf(xb[2], xb[2], ssq); ssq = fmaf(xb[3], xb[3], ssq);
    bf16x8 b0 = *(const bf16x8*)(wp + s * 32);
    bf16x8 b1 = *(const bf16x8*)(wp + (size_t)16 * Dn + s * 32);
    acc0 = __builtin_amdgcn_mfma_f32_16x16x32_bf16(af, b0, acc0, 0, 0, 0);
    acc1 = __builtin_amdgcn_mfma_f32_16x16x32_bf16(af, b1, acc1, 0, 0, 0);
  }
  // row sumsq: lane (mr,q) holds partial of row row0+mr
  ssq += __shfl_xor(ssq, 16);
  ssq += __shfl_xor(ssq, 32);
  float invb = 1.f / fmaxf(sqrtf(ssq), EPSF);   // invnorm of row row0+mr
  float cs0 = 0.f, cs1 = 0.f;
  bf16x4 v40, v41;
#pragma unroll
  for (int r = 0; r < 4; ++r) {
    float inv = __shfl(invb, q * 4 + r);        // invnorm of row row0+q*4+r
    float v0 = acc0[r] * inv, v1 = acc1[r] * inv;
    float mx = fmaxf(v0, v1);                   // max over k: across 16 k-lanes
    mx = fmaxf(mx, __shfl_xor(mx, 1));
    mx = fmaxf(mx, __shfl_xor(mx, 2));
    mx = fmaxf(mx, __shfl_xor(mx, 4));
    mx = fmaxf(mx, __shfl_xor(mx, 8));
    float e0 = __expf(v0 - mx), e1 = __expf(v1 - mx);
    float sm = e0 + e1;
    sm += __shfl_xor(sm, 1); sm += __shfl_xor(sm, 2);
    sm += __shfl_xor(sm, 4); sm += __shfl_xor(sm, 8);
    float rs = 1.f / sm;
    float sa0 = e0 * rs, sa1 = e1 * rs;
    v40[r] = (__bf16)(sa0 * inv);               // sa' = sa * invnorm
    v41[r] = (__bf16)(sa1 * inv);
    cs0 += sa0; cs1 += sa1;
  }
  int mloc = row0 & 511;                        // m-offset within this b
  __bf16* st = saT + ((size_t)(b * Kn + mr)) * Mn + mloc + q * 4;
  *(bf16x4*)st = v40;
  *(bf16x4*)(st + (size_t)16 * Mn) = v41;
  cs0 += __shfl_xor(cs0, 16); cs0 += __shfl_xor(cs0, 32);
  cs1 += __shfl_xor(cs1, 16); cs1 += __shfl_xor(cs1, 32);
  if (lane < 16) {
    atomicAdd(&colsum[b * Kn + mr], cs0);
    atomicAdd(&colsum[b * Kn + mr + 16], cs1);
  }
}

// ---------------- K3: agg = saT @ x via MFMA, x frags DIRECT from global -------
// Block = (b, 128-d chunk), 4 waves x 2 d-tiles. saT staged once to LDS
// (stride 520 bf16 -> conflict-free b128 phases); ONE barrier total, so the
// compiler can software-pipeline the m-loop (no syncthreads inside).
// B-frag: lane(n,q) holds x[m0+8q+j][d0+n] -- 8 scalar loads, each instr's
// 16 consecutive-n lanes cover exactly one fully-used 64B line.
#define AS 520
__global__ __launch_bounds__(256) void k3_agg(const float* __restrict__ x,
                                              const __bf16* __restrict__ saT,
                                              const float* __restrict__ colsum,
                                              const float* __restrict__ cent,
                                              float* __restrict__ vlad,
                                              float* __restrict__ ssq) {
  __shared__ __bf16 sal[Kn * AS];   // ~33 KB
  __shared__ float csl[Kn];
  int b = blockIdx.x >> 4;
  int dchunk = (blockIdx.x & 15) * 128;
  int t = threadIdx.x;
  const __bf16* sg = saT + (size_t)b * Kn * Mn;
#pragma unroll
  for (int i = 0; i < 8; ++i) {
    int u = t + 256 * i;            // 2048 units of 8 bf16
    int kr = u >> 6, off = (u & 63) * 8;
    *(bf16x8*)&sal[kr * AS + off] = *(const bf16x8*)(sg + (size_t)kr * Mn + off);
  }
  if (t < Kn) csl[t] = colsum[b * Kn + t];
  __syncthreads();
  int w = t >> 6, lane = t & 63;
  int n = lane & 15, q = lane >> 4;
  int d0 = dchunk + w * 32;
  const float* xg = x + (size_t)b * Mn * Dn;
  f32x4 acc[2][2] = {};
  for (int m0 = 0; m0 < Mn; m0 += 32) {
    bf16x8 a0 = *(const bf16x8*)&sal[n * AS + m0 + q * 8];
    bf16x8 a1 = *(const bf16x8*)&sal[(n + 16) * AS + m0 + q * 8];
#pragma unroll
    for (int dt = 0; dt < 2; ++dt) {
      const float* xp = xg + (size_t)(m0 + q * 8) * Dn + d0 + dt * 16 + n;
      bf16x8 bv;
#pragma unroll
      for (int j = 0; j < 8; ++j) bv[j] = (__bf16)xp[(size_t)j * Dn];
      acc[dt][0] = __builtin_amdgcn_mfma_f32_16x16x32_bf16(a0, bv, acc[dt][0], 0, 0, 0);
      acc[dt][1] = __builtin_amdgcn_mfma_f32_16x16x32_bf16(a1, bv, acc[dt][1], 0, 0, 0);
    }
  }
  // epilogue: vlad = agg - colsum*cent (fp32), store + ssq partial atomics
#pragma unroll
  for (int dt = 0; dt < 2; ++dt) {
#pragma unroll
    for (int kt = 0; kt < 2; ++kt) {
#pragma unroll
      for (int r = 0; r < 4; ++r) {
        int k = kt * 16 + q * 4 + r;
        int d = d0 + dt * 16 + n;
        float vv = acc[dt][kt][r] - csl[k] * cent[(size_t)k * Dn + d];
        vlad[((size_t)(b * Kn + k)) * Dn + d] = vv;
        float sq = vv * vv;
        sq += __shfl_xor(sq, 1); sq += __shfl_xor(sq, 2);
        sq += __shfl_xor(sq, 4); sq += __shfl_xor(sq, 8);
        if (n == 0) atomicAdd(&ssq[b * Kn + k], sq);
      }
    }
  }
}

// ---------------- K4: intra-normalize per (b,k) + global L2 normalize, in place
__global__ __launch_bounds__(256) void k4_norm(float* __restrict__ out,
                                               const float* __restrict__ ssq) {
  __shared__ float rk[Kn];
  __shared__ float us[Kn];
  int b = blockIdx.x >> 4;
  int t = threadIdx.x;
  if (t < Kn) {
    float ss = ssq[b * Kn + t];
    float r = 1.f / fmaxf(sqrtf(ss), EPSF);
    rk[t] = r;
    us[t] = ss * r * r;   // = ||u_k||^2 after intra-norm
  }
  __syncthreads();
  float S = 0.f;
#pragma unroll
  for (int k = 0; k < Kn; ++k) S += us[k];
  float s = 1.f / fmaxf(sqrtf(S), EPSF);
  int chunk = blockIdx.x & 15;
  size_t base = (size_t)b * (Kn * Dn) + (size_t)chunk * 4096;
  f32x4* p = (f32x4*)(out + base);
#pragma unroll
  for (int i = 0; i < 4; ++i) {
    int idx = t + 256 * i;                        // float4 index, 0..1023
    int k = (chunk * 4096 + idx * 4) >> 11;       // 2048 floats per k
    f32x4 v = p[idx];
    float sc = rk[k] * s;
    v[0] *= sc; v[1] *= sc; v[2] *= sc; v[3] *= sc;
    p[idx] = v;
  }
}

extern "C" void kernel_launch(void* const* d_in, const int* in_sizes, int n_in,
                              void* d_out, int out_size, void* d_ws, size_t ws_size,
                              hipStream_t stream) {
  const float* x = (const float*)d_in[0];
  const float* W = (const float*)d_in[1];
  const float* cent = (const float*)d_in[2];
  float* out = (float*)d_out;
  char* ws = (char*)d_ws;
  // ws layout: Wb (128K) | colsum (8K) | ssq (8K) | saT (8M bf16, k-major)
  __bf16* Wb = (__bf16*)ws;
  float* colsum = (float*)(ws + 131072);
  float* ssqb = (float*)(ws + 131072 + 8192);
  __bf16* saT = (__bf16*)(ws + 131072 + 16384);
  hipLaunchKernelGGL(k0_prep, dim3(256), dim3(256), 0, stream, W, Wb, colsum, ssqb);
  hipLaunchKernelGGL(k1_logits_softmax, dim3(512), dim3(256), 0, stream, x, Wb, saT, colsum);
  hipLaunchKernelGGL(k3_agg, dim3(1024), dim3(256), 0, stream, x, saT, colsum, cent, out, ssqb);
  hipLaunchKernelGGL(k4_norm, dim3(1024), dim3(256), 0, stream, out, ssqb);
}

// Round 4
// 438.910 us; speedup vs baseline: 1.1355x; 1.0202x over previous
//
#include <hip/hip_runtime.h>
#include <hip/hip_bf16.h>
#include <cstdint>
#include <cstddef>

#define Bn 64
#define Mn 512
#define Dn 2048
#define Kn 32
#define EPSF 1e-12f

typedef __attribute__((ext_vector_type(8))) __bf16 bf16x8;
typedef __attribute__((ext_vector_type(4))) __bf16 bf16x4;
typedef __attribute__((ext_vector_type(4))) float f32x4;

// ---------------- K1: logits (bf16 MFMA) + fused softmax -> saT bf16 + colsum --
// One wave per 16 rows. Blocks iterate b DESCENDING so the LLC (256 MiB = |x|)
// ends holding the low-b half of x most-recently -- k3 then reads ascending
// and hits LLC instead of HBM (LRU streaming pathology avoided).
// W converted f32->bf16 in-register (L2-resident; bit-identical to a pre-pass).
// C/D layout: lane&15 = k, (lane>>4)*4+r = m. Lane holds 4 consecutive m of one
// k, so the k-major saT store is a free transpose (8 B stores).
__global__ __launch_bounds__(256) void k1_logits_softmax(const float* __restrict__ x,
                                                         const float* __restrict__ W,
                                                         __bf16* __restrict__ saT,
                                                         float* __restrict__ colsum) {
  int wv = threadIdx.x >> 6, lane = threadIdx.x & 63;
  int mr = lane & 15, q = lane >> 4;
  int blk = 511 - blockIdx.x;              // <-- descending-b sweep (LLC recency)
  int row0 = (blk * 4 + wv) * 16;
  int b = row0 >> 9;                       // 512 rows per b
  const float* xp = x + (size_t)(row0 + mr) * Dn + q * 8;
  const float* wp0 = W + (size_t)mr * Dn + q * 8;
  const float* wp1 = W + (size_t)(mr + 16) * Dn + q * 8;
  f32x4 acc0 = {0.f, 0.f, 0.f, 0.f};
  f32x4 acc1 = {0.f, 0.f, 0.f, 0.f};
  float ssq = 0.f;
#pragma unroll 2
  for (int s = 0; s < 64; ++s) {
    f32x4 xa = *(const f32x4*)(xp + s * 32);
    f32x4 xb = *(const f32x4*)(xp + s * 32 + 4);
    bf16x8 af;
    af[0] = (__bf16)xa[0]; af[1] = (__bf16)xa[1];
    af[2] = (__bf16)xa[2]; af[3] = (__bf16)xa[3];
    af[4] = (__bf16)xb[0]; af[5] = (__bf16)xb[1];
    af[6] = (__bf16)xb[2]; af[7] = (__bf16)xb[3];
    ssq = fmaf(xa[0], xa[0], ssq); ssq = fmaf(xa[1], xa[1], ssq);
    ssq = fmaf(xa[2], xa[2], ssq); ssq = fmaf(xa[3], xa[3], ssq);
    ssq = fmaf(xb[0], xb[0], ssq); ssq = fmaf(xb[1], xb[1], ssq);
    ssq = fmaf(xb[2], xb[2], ssq); ssq = fmaf(xb[3], xb[3], ssq);
    f32x4 wa = *(const f32x4*)(wp0 + s * 32);
    f32x4 wb = *(const f32x4*)(wp0 + s * 32 + 4);
    bf16x8 b0;
    b0[0] = (__bf16)wa[0]; b0[1] = (__bf16)wa[1];
    b0[2] = (__bf16)wa[2]; b0[3] = (__bf16)wa[3];
    b0[4] = (__bf16)wb[0]; b0[5] = (__bf16)wb[1];
    b0[6] = (__bf16)wb[2]; b0[7] = (__bf16)wb[3];
    f32x4 wc = *(const f32x4*)(wp1 + s * 32);
    f32x4 wd = *(const f32x4*)(wp1 + s * 32 + 4);
    bf16x8 b1;
    b1[0] = (__bf16)wc[0]; b1[1] = (__bf16)wc[1];
    b1[2] = (__bf16)wc[2]; b1[3] = (__bf16)wc[3];
    b1[4] = (__bf16)wd[0]; b1[5] = (__bf16)wd[1];
    b1[6] = (__bf16)wd[2]; b1[7] = (__bf16)wd[3];
    acc0 = __builtin_amdgcn_mfma_f32_16x16x32_bf16(af, b0, acc0, 0, 0, 0);
    acc1 = __builtin_amdgcn_mfma_f32_16x16x32_bf16(af, b1, acc1, 0, 0, 0);
  }
  // row sumsq: lane (mr,q) holds partial of row row0+mr
  ssq += __shfl_xor(ssq, 16);
  ssq += __shfl_xor(ssq, 32);
  float invb = 1.f / fmaxf(sqrtf(ssq), EPSF);   // invnorm of row row0+mr
  float cs0 = 0.f, cs1 = 0.f;
  bf16x4 v40, v41;
#pragma unroll
  for (int r = 0; r < 4; ++r) {
    float inv = __shfl(invb, q * 4 + r);        // invnorm of row row0+q*4+r
    float v0 = acc0[r] * inv, v1 = acc1[r] * inv;
    float mx = fmaxf(v0, v1);                   // max over k: across 16 k-lanes
    mx = fmaxf(mx, __shfl_xor(mx, 1));
    mx = fmaxf(mx, __shfl_xor(mx, 2));
    mx = fmaxf(mx, __shfl_xor(mx, 4));
    mx = fmaxf(mx, __shfl_xor(mx, 8));
    float e0 = __expf(v0 - mx), e1 = __expf(v1 - mx);
    float sm = e0 + e1;
    sm += __shfl_xor(sm, 1); sm += __shfl_xor(sm, 2);
    sm += __shfl_xor(sm, 4); sm += __shfl_xor(sm, 8);
    float rs = 1.f / sm;
    float sa0 = e0 * rs, sa1 = e1 * rs;
    v40[r] = (__bf16)(sa0 * inv);               // sa' = sa * invnorm
    v41[r] = (__bf16)(sa1 * inv);
    cs0 += sa0; cs1 += sa1;
  }
  int mloc = row0 & 511;                        // m-offset within this b
  __bf16* st = saT + ((size_t)(b * Kn + mr)) * Mn + mloc + q * 4;
  *(bf16x4*)st = v40;
  *(bf16x4*)(st + (size_t)16 * Mn) = v41;
  cs0 += __shfl_xor(cs0, 16); cs0 += __shfl_xor(cs0, 32);
  cs1 += __shfl_xor(cs1, 16); cs1 += __shfl_xor(cs1, 32);
  if (lane < 16) {
    atomicAdd(&colsum[b * Kn + mr], cs0);
    atomicAdd(&colsum[b * Kn + mr + 16], cs1);
  }
}

// ---------------- K3: agg = saT @ x via MFMA, x frags DIRECT from global -------
// Natural ASCENDING b order: reads x low-b first = k1's most-recent LLC lines.
// saT staged once to LDS (stride 520 bf16 -> conflict-free b128); ONE barrier,
// no syncthreads in the m-loop (compiler free to software-pipeline).
// B-frag: lane(n,q) holds x[m0+8q+j][d0+n]; each load instr's 16 consecutive-n
// lanes cover one fully-used 64B line.
#define AS 520
__global__ __launch_bounds__(256) void k3_agg(const float* __restrict__ x,
                                              const __bf16* __restrict__ saT,
                                              const float* __restrict__ colsum,
                                              const float* __restrict__ cent,
                                              float* __restrict__ vlad,
                                              float* __restrict__ ssq) {
  __shared__ __bf16 sal[Kn * AS];   // ~33 KB
  __shared__ float csl[Kn];
  int b = blockIdx.x >> 4;
  int dchunk = (blockIdx.x & 15) * 128;
  int t = threadIdx.x;
  const __bf16* sg = saT + (size_t)b * Kn * Mn;
#pragma unroll
  for (int i = 0; i < 8; ++i) {
    int u = t + 256 * i;            // 2048 units of 8 bf16
    int kr = u >> 6, off = (u & 63) * 8;
    *(bf16x8*)&sal[kr * AS + off] = *(const bf16x8*)(sg + (size_t)kr * Mn + off);
  }
  if (t < Kn) csl[t] = colsum[b * Kn + t];
  __syncthreads();
  int w = t >> 6, lane = t & 63;
  int n = lane & 15, q = lane >> 4;
  int d0 = dchunk + w * 32;
  const float* xg = x + (size_t)b * Mn * Dn;
  f32x4 acc[2][2] = {};
  for (int m0 = 0; m0 < Mn; m0 += 32) {
    bf16x8 a0 = *(const bf16x8*)&sal[n * AS + m0 + q * 8];
    bf16x8 a1 = *(const bf16x8*)&sal[(n + 16) * AS + m0 + q * 8];
#pragma unroll
    for (int dt = 0; dt < 2; ++dt) {
      const float* xp = xg + (size_t)(m0 + q * 8) * Dn + d0 + dt * 16 + n;
      bf16x8 bv;
#pragma unroll
      for (int j = 0; j < 8; ++j) bv[j] = (__bf16)xp[(size_t)j * Dn];
      acc[dt][0] = __builtin_amdgcn_mfma_f32_16x16x32_bf16(a0, bv, acc[dt][0], 0, 0, 0);
      acc[dt][1] = __builtin_amdgcn_mfma_f32_16x16x32_bf16(a1, bv, acc[dt][1], 0, 0, 0);
    }
  }
  // epilogue: vlad = agg - colsum*cent (fp32), store + ssq partial atomics
#pragma unroll
  for (int dt = 0; dt < 2; ++dt) {
#pragma unroll
    for (int kt = 0; kt < 2; ++kt) {
#pragma unroll
      for (int r = 0; r < 4; ++r) {
        int k = kt * 16 + q * 4 + r;
        int d = d0 + dt * 16 + n;
        float vv = acc[dt][kt][r] - csl[k] * cent[(size_t)k * Dn + d];
        vlad[((size_t)(b * Kn + k)) * Dn + d] = vv;
        float sq = vv * vv;
        sq += __shfl_xor(sq, 1); sq += __shfl_xor(sq, 2);
        sq += __shfl_xor(sq, 4); sq += __shfl_xor(sq, 8);
        if (n == 0) atomicAdd(&ssq[b * Kn + k], sq);
      }
    }
  }
}

// ---------------- K4: intra-normalize per (b,k) + global L2 normalize, in place
__global__ __launch_bounds__(256) void k4_norm(float* __restrict__ out,
                                               const float* __restrict__ ssq) {
  __shared__ float rk[Kn];
  __shared__ float us[Kn];
  int b = blockIdx.x >> 4;
  int t = threadIdx.x;
  if (t < Kn) {
    float ss = ssq[b * Kn + t];
    float r = 1.f / fmaxf(sqrtf(ss), EPSF);
    rk[t] = r;
    us[t] = ss * r * r;   // = ||u_k||^2 after intra-norm
  }
  __syncthreads();
  float S = 0.f;
#pragma unroll
  for (int k = 0; k < Kn; ++k) S += us[k];
  float s = 1.f / fmaxf(sqrtf(S), EPSF);
  int chunk = blockIdx.x & 15;
  size_t base = (size_t)b * (Kn * Dn) + (size_t)chunk * 4096;
  f32x4* p = (f32x4*)(out + base);
#pragma unroll
  for (int i = 0; i < 4; ++i) {
    int idx = t + 256 * i;                        // float4 index, 0..1023
    int k = (chunk * 4096 + idx * 4) >> 11;       // 2048 floats per k
    f32x4 v = p[idx];
    float sc = rk[k] * s;
    v[0] *= sc; v[1] *= sc; v[2] *= sc; v[3] *= sc;
    p[idx] = v;
  }
}

extern "C" void kernel_launch(void* const* d_in, const int* in_sizes, int n_in,
                              void* d_out, int out_size, void* d_ws, size_t ws_size,
                              hipStream_t stream) {
  const float* x = (const float*)d_in[0];
  const float* W = (const float*)d_in[1];
  const float* cent = (const float*)d_in[2];
  float* out = (float*)d_out;
  char* ws = (char*)d_ws;
  // ws layout: colsum (8K) | ssq (8K) | saT (8M bf16, k-major)
  float* colsum = (float*)ws;
  float* ssqb = (float*)(ws + 8192);
  __bf16* saT = (__bf16*)(ws + 16384);
  hipMemsetAsync(ws, 0, 16384, stream);   // zero colsum+ssq (graph-capturable)
  hipLaunchKernelGGL(k1_logits_softmax, dim3(512), dim3(256), 0, stream, x, W, saT, colsum);
  hipLaunchKernelGGL(k3_agg, dim3(1024), dim3(256), 0, stream, x, saT, colsum, cent, out, ssqb);
  hipLaunchKernelGGL(k4_norm, dim3(1024), dim3(256), 0, stream, out, ssqb);
}